// Round 1
// baseline (2178.572 us; speedup 1.0000x reference)
//
#include <hip/hip_runtime.h>
#include <cmath>

#define CH 32
#define NBASIS 8
#define NPATH 11

__device__ __forceinline__ float silu_f(float x) {
    return x / (1.0f + __expf(-x));
}

// One edge handled by 32 threads (one per channel c).
__global__ __launch_bounds__(256) void edge_kernel(
    const float* __restrict__ rij,     // [E,3]
    const float* __restrict__ x0,      // [N,C]
    const float* __restrict__ x1,      // [N,C,3]
    const float* __restrict__ x2,      // [N,C,9]
    const int*   __restrict__ idx_i,   // [E]
    const int*   __restrict__ idx_j,   // [E]
    const float* __restrict__ W_rbf,   // [NBASIS, NPATH*C]
    const float* __restrict__ b_rbf,   // [NPATH*C]
    float* __restrict__ a0,            // [N,C]
    float* __restrict__ a1,            // [N,C,3]
    float* __restrict__ a2,            // [N,C,9]
    int E)
{
    int t = blockIdx.x * blockDim.x + threadIdx.x;
    int e = t >> 5;
    int c = t & 31;
    if (e >= E) return;

    float rx = rij[e * 3 + 0], ry = rij[e * 3 + 1], rz = rij[e * 3 + 2];
    float dn = sqrtf(rx * rx + ry * ry + rz * rz);
    float d = fmaxf(dn, 1e-6f);
    float inv = 1.0f / d;
    float h[3] = {rx * inv, ry * inv, rz * inv};

    // Gaussian RBF: centers = linspace(0, 5, 8); exp(-(d-ck)^2/0.25)
    float rbf[NBASIS];
#pragma unroll
    for (int k = 0; k < NBASIS; k++) {
        float ck = 5.0f * (float)k / (float)(NBASIS - 1);
        float del = d - ck;
        rbf[k] = __expf(-4.0f * del * del);
    }
    // cosine cutoff
    float dc = fminf(d, 5.0f);
    float fc = 0.5f * (__cosf((float)M_PI * dc * 0.2f) + 1.0f);
    // fold the 1/NORM_FACTOR (=0.1) into the filters (messages are linear in filt)
    float scale = fc * 0.1f;

    float f[NPATH];
#pragma unroll
    for (int p = 0; p < NPATH; p++) {
        int col = p * CH + c;
        float acc = b_rbf[col];
#pragma unroll
        for (int k = 0; k < NBASIS; k++)
            acc = fmaf(rbf[k], W_rbf[k * (NPATH * CH) + col], acc);
        f[p] = acc * scale;
    }

    int j = idx_j[e];
    int i = idx_i[e];

    float xj0 = x0[j * CH + c];
    float xv[3];
#pragma unroll
    for (int a = 0; a < 3; a++) xv[a] = x1[(j * CH + c) * 3 + a];
    float T[9];
#pragma unroll
    for (int q = 0; q < 9; q++) T[q] = x2[(j * CH + c) * 9 + q];

    float x1r = xv[0] * h[0] + xv[1] * h[1] + xv[2] * h[2];
    float x2r[3];
#pragma unroll
    for (int a = 0; a < 3; a++)
        x2r[a] = T[a * 3 + 0] * h[0] + T[a * 3 + 1] * h[1] + T[a * 3 + 2] * h[2];
    float x2rr = x2r[0] * h[0] + x2r[1] * h[1] + x2r[2] * h[2];

    // way-0 message
    float m0 = f[0] * xj0 + f[5] * x1r + f[10] * x2rr;
    // way-1 message
    float s01 = f[1] * xj0 + f[6] * x1r;
    float m1[3];
#pragma unroll
    for (int a = 0; a < 3; a++)
        m1[a] = s01 * h[a] + f[3] * xv[a] + f[8] * x2r[a];
    // way-2 message
    float f2x = f[2] * xj0;
    float m2[9];
#pragma unroll
    for (int a = 0; a < 3; a++) {
#pragma unroll
        for (int b = 0; b < 3; b++) {
            m2[a * 3 + b] = f2x * h[a] * h[b] + f[4] * xv[a] * h[b]
                          + f[7] * T[a * 3 + b] + f[9] * x2r[a] * h[b];
        }
    }

    atomicAdd(&a0[i * CH + c], m0);
#pragma unroll
    for (int a = 0; a < 3; a++) atomicAdd(&a1[(i * CH + c) * 3 + a], m1[a]);
#pragma unroll
    for (int q = 0; q < 9; q++) atomicAdd(&a2[(i * CH + c) * 9 + q], m2[q]);
}

// 8 nodes per 256-thread block; thread (ln, d) handles output channel d of node ln.
__global__ __launch_bounds__(256) void node_kernel(
    const float* __restrict__ a0g, const float* __restrict__ a1g, const float* __restrict__ a2g,
    const float* __restrict__ x0, const float* __restrict__ x1, const float* __restrict__ x2,
    const float* __restrict__ Wmix0, const float* __restrict__ Wmix1, const float* __restrict__ Wmix2,
    const float* __restrict__ coupling,   // [8,C]
    const float* __restrict__ Wg0, const float* __restrict__ Wg1, const float* __restrict__ Wg2,
    const float* __restrict__ bg0, const float* __restrict__ bg1, const float* __restrict__ bg2,
    float* __restrict__ out, int N)
{
    const int NN = 8;
    __shared__ float sa0[NN][CH];
    __shared__ float sa1[NN][CH][3];
    __shared__ float sa2[NN][CH][9];
    __shared__ float sy0[NN][CH];

    int ln = threadIdx.x >> 5;
    int d  = threadIdx.x & 31;
    int n  = blockIdx.x * NN + ln;
    bool valid = (n < N);

    float A0 = 0.0f, A1[3] = {0, 0, 0}, A2[9] = {0, 0, 0, 0, 0, 0, 0, 0, 0};
    if (valid) {
        A0 = a0g[n * CH + d];
#pragma unroll
        for (int a = 0; a < 3; a++) A1[a] = a1g[(n * CH + d) * 3 + a];
#pragma unroll
        for (int q = 0; q < 9; q++) A2[q] = a2g[(n * CH + d) * 9 + q];
    }
    sa0[ln][d] = A0;
#pragma unroll
    for (int a = 0; a < 3; a++) sa1[ln][d][a] = A1[a];
#pragma unroll
    for (int q = 0; q < 9; q++) sa2[ln][d][q] = A2[q];
    __syncthreads();

    // ---- y0 ----
    float y0 = 0.0f;
#pragma unroll 8
    for (int cc = 0; cc < CH; cc++) y0 = fmaf(sa0[ln][cc], Wmix0[cc * CH + d], y0);
    float cp0 = coupling[0 * CH + d], cp1 = coupling[1 * CH + d], cp2 = coupling[2 * CH + d];
    float cp3 = coupling[3 * CH + d], cp4 = coupling[4 * CH + d], cp5 = coupling[5 * CH + d];
    float cp6 = coupling[6 * CH + d], cp7 = coupling[7 * CH + d];
    float n1 = A1[0] * A1[0] + A1[1] * A1[1] + A1[2] * A1[2];
    float n2 = 0.0f;
#pragma unroll
    for (int q = 0; q < 9; q++) n2 = fmaf(A2[q], A2[q], n2);
    y0 += cp0 * A0 * A0 + cp3 * n1 + cp6 * n2;
    sy0[ln][d] = y0;

    // ---- y1 ----
    float y1[3] = {0, 0, 0};
#pragma unroll 4
    for (int cc = 0; cc < CH; cc++) {
        float w = Wmix1[cc * CH + d];
#pragma unroll
        for (int a = 0; a < 3; a++) y1[a] = fmaf(sa1[ln][cc][a], w, y1[a]);
    }
#pragma unroll
    for (int a = 0; a < 3; a++) {
        float a2a1 = A2[a * 3 + 0] * A1[0] + A2[a * 3 + 1] * A1[1] + A2[a * 3 + 2] * A1[2];
        y1[a] += cp1 * A0 * A1[a] + cp5 * a2a1;
    }

    // ---- y2 ----
    float y2[9] = {0, 0, 0, 0, 0, 0, 0, 0, 0};
#pragma unroll 2
    for (int cc = 0; cc < CH; cc++) {
        float w = Wmix2[cc * CH + d];
#pragma unroll
        for (int q = 0; q < 9; q++) y2[q] = fmaf(sa2[ln][cc][q], w, y2[q]);
    }
#pragma unroll
    for (int a = 0; a < 3; a++) {
#pragma unroll
        for (int b = 0; b < 3; b++) {
            float a2a2 = A2[a * 3 + 0] * A2[0 * 3 + b] + A2[a * 3 + 1] * A2[1 * 3 + b]
                       + A2[a * 3 + 2] * A2[2 * 3 + b];
            y2[a * 3 + b] += cp2 * A0 * A2[a * 3 + b] + cp4 * A1[a] * A1[b] + cp7 * a2a2;
        }
    }

    __syncthreads();  // sy0 complete

    // ---- gates ----
    float g0 = bg0[d], g1 = bg1[d], g2 = bg2[d];
#pragma unroll 8
    for (int cc = 0; cc < CH; cc++) {
        float yv = sy0[ln][cc];
        g0 = fmaf(yv, Wg0[cc * CH + d], g0);
        g1 = fmaf(yv, Wg1[cc * CH + d], g1);
        g2 = fmaf(yv, Wg2[cc * CH + d], g2);
    }
    g0 = silu_f(g0);
    g1 = silu_f(g1);
    g2 = silu_f(g2);

    if (valid) {
        float* o = &out[(size_t)(n * CH + d) * 13];
        o[0] = x0[n * CH + d] + g0;
#pragma unroll
        for (int a = 0; a < 3; a++) o[1 + a] = x1[(n * CH + d) * 3 + a] + y1[a] * g1;
#pragma unroll
        for (int q = 0; q < 9; q++) o[4 + q] = x2[(n * CH + d) * 9 + q] + y2[q] * g2;
    }
}

extern "C" void kernel_launch(void* const* d_in, const int* in_sizes, int n_in,
                              void* d_out, int out_size, void* d_ws, size_t ws_size,
                              hipStream_t stream) {
    const float* rij      = (const float*)d_in[0];
    const float* x0       = (const float*)d_in[1];
    const float* x1       = (const float*)d_in[2];
    const float* x2       = (const float*)d_in[3];
    const int*   idx_i    = (const int*)d_in[4];
    const int*   idx_j    = (const int*)d_in[5];
    const float* W_rbf    = (const float*)d_in[6];
    const float* b_rbf    = (const float*)d_in[7];
    const float* Wmix0    = (const float*)d_in[8];
    const float* Wmix1    = (const float*)d_in[9];
    const float* Wmix2    = (const float*)d_in[10];
    const float* coupling = (const float*)d_in[11];
    const float* Wg0      = (const float*)d_in[12];
    const float* Wg1      = (const float*)d_in[13];
    const float* Wg2      = (const float*)d_in[14];
    const float* bg0      = (const float*)d_in[15];
    const float* bg1      = (const float*)d_in[16];
    const float* bg2      = (const float*)d_in[17];

    int E = in_sizes[4];
    int N = in_sizes[1] / CH;

    float* a0 = (float*)d_ws;
    float* a1 = a0 + (size_t)N * CH;
    float* a2 = a1 + (size_t)N * CH * 3;
    size_t abytes = (size_t)N * CH * 13 * sizeof(float);
    hipMemsetAsync(d_ws, 0, abytes, stream);

    int ethreads = E * 32;
    int eblocks = (ethreads + 255) / 256;
    edge_kernel<<<eblocks, 256, 0, stream>>>(rij, x0, x1, x2, idx_i, idx_j,
                                             W_rbf, b_rbf, a0, a1, a2, E);

    int nblocks = (N + 7) / 8;
    node_kernel<<<nblocks, 256, 0, stream>>>(a0, a1, a2, x0, x1, x2,
                                             Wmix0, Wmix1, Wmix2, coupling,
                                             Wg0, Wg1, Wg2, bg0, bg1, bg2,
                                             (float*)d_out, N);
}

// Round 2
// 337.944 us; speedup vs baseline: 6.4466x; 6.4466x over previous
//
#include <hip/hip_runtime.h>
#include <cmath>

#define CH 32
#define NBASIS 8
#define NPATH 11

__device__ __forceinline__ float silu_f(float x) {
    return x / (1.0f + __expf(-x));
}

// ---------- CSR build ----------
__global__ __launch_bounds__(256) void hist_kernel(const int* __restrict__ idx_i,
                                                   int* __restrict__ counts, int E) {
    int e = blockIdx.x * blockDim.x + threadIdx.x;
    if (e < E) atomicAdd(&counts[idx_i[e]], 1);
}

// Single-block exclusive scan over N counts -> offsets[N+1], cursor[N]
__global__ __launch_bounds__(1024) void scan_kernel(const int* __restrict__ counts,
                                                    int* __restrict__ offsets,
                                                    int* __restrict__ cursor, int N) {
    __shared__ int part[1024];
    int t = threadIdx.x;
    int per = (N + 1023) / 1024;
    int start = t * per;
    int local = 0;
    for (int k = 0; k < per; k++) {
        int idx = start + k;
        if (idx < N) local += counts[idx];
    }
    part[t] = local;
    __syncthreads();
    // Hillis-Steele inclusive scan
    for (int off = 1; off < 1024; off <<= 1) {
        int v = (t >= off) ? part[t - off] : 0;
        __syncthreads();
        part[t] += v;
        __syncthreads();
    }
    int base = (t == 0) ? 0 : part[t - 1];
    for (int k = 0; k < per; k++) {
        int idx = start + k;
        if (idx < N) {
            offsets[idx] = base;
            cursor[idx]  = base;
            base += counts[idx];
        }
    }
    if (t == 0) offsets[N] = part[1023];
}

__global__ __launch_bounds__(256) void fill_kernel(const int* __restrict__ idx_i,
                                                   int* __restrict__ cursor,
                                                   int* __restrict__ perm, int E) {
    int e = blockIdx.x * blockDim.x + threadIdx.x;
    if (e < E) {
        int pos = atomicAdd(&cursor[idx_i[e]], 1);
        perm[pos] = e;
    }
}

// ---------- fused gather + self-interaction ----------
// 8 nodes per 256-thread block; (ln, c) = (node-slot, channel).
__global__ __launch_bounds__(256) void fused_kernel(
    const float* __restrict__ rij,     // [E,3]
    const float* __restrict__ x0,      // [N,C]
    const float* __restrict__ x1,      // [N,C,3]
    const float* __restrict__ x2,      // [N,C,9]
    const int*   __restrict__ idx_j,   // [E]
    const int*   __restrict__ offsets, // [N+1]
    const int*   __restrict__ perm,    // [E]
    const float* __restrict__ W_rbf,   // [NBASIS, NPATH*C]
    const float* __restrict__ b_rbf,   // [NPATH*C]
    const float* __restrict__ Wmix0, const float* __restrict__ Wmix1, const float* __restrict__ Wmix2,
    const float* __restrict__ coupling,
    const float* __restrict__ Wg0, const float* __restrict__ Wg1, const float* __restrict__ Wg2,
    const float* __restrict__ bg0, const float* __restrict__ bg1, const float* __restrict__ bg2,
    float* __restrict__ out, int N)
{
    const int NN = 8;
    __shared__ float sa0[NN][CH];
    __shared__ float sa1[NN][CH][3];
    __shared__ float sa2[NN][CH][9];
    __shared__ float sy0[NN][CH];

    int ln = threadIdx.x >> 5;
    int c  = threadIdx.x & 31;
    int n  = blockIdx.x * NN + ln;
    bool valid = (n < N);

    float A0 = 0.0f, A1[3] = {0, 0, 0}, A2[9] = {0, 0, 0, 0, 0, 0, 0, 0, 0};

    int kbeg = 0, kend = 0;
    if (valid) { kbeg = offsets[n]; kend = offsets[n + 1]; }

    for (int k = kbeg; k < kend; k++) {
        int e = perm[k];
        float rx = rij[e * 3 + 0], ry = rij[e * 3 + 1], rz = rij[e * 3 + 2];
        float dn = sqrtf(rx * rx + ry * ry + rz * rz);
        float d = fmaxf(dn, 1e-6f);
        float inv = 1.0f / d;
        float h[3] = {rx * inv, ry * inv, rz * inv};

        float rbf[NBASIS];
#pragma unroll
        for (int kk = 0; kk < NBASIS; kk++) {
            float ck = 5.0f * (float)kk / (float)(NBASIS - 1);
            float del = d - ck;
            rbf[kk] = __expf(-4.0f * del * del);
        }
        float dc = fminf(d, 5.0f);
        float fc = 0.5f * (__cosf((float)M_PI * dc * 0.2f) + 1.0f);
        float scale = fc * 0.1f;   // fold 1/NORM_FACTOR into filters

        float f[NPATH];
#pragma unroll
        for (int p = 0; p < NPATH; p++) {
            int col = p * CH + c;
            float acc = b_rbf[col];
#pragma unroll
            for (int kk = 0; kk < NBASIS; kk++)
                acc = fmaf(rbf[kk], W_rbf[kk * (NPATH * CH) + col], acc);
            f[p] = acc * scale;
        }

        int j = idx_j[e];
        float xj0 = x0[j * CH + c];
        float xv[3];
#pragma unroll
        for (int a = 0; a < 3; a++) xv[a] = x1[(j * CH + c) * 3 + a];
        float T[9];
#pragma unroll
        for (int q = 0; q < 9; q++) T[q] = x2[(j * CH + c) * 9 + q];

        float x1r = xv[0] * h[0] + xv[1] * h[1] + xv[2] * h[2];
        float x2r[3];
#pragma unroll
        for (int a = 0; a < 3; a++)
            x2r[a] = T[a * 3 + 0] * h[0] + T[a * 3 + 1] * h[1] + T[a * 3 + 2] * h[2];
        float x2rr = x2r[0] * h[0] + x2r[1] * h[1] + x2r[2] * h[2];

        A0 += f[0] * xj0 + f[5] * x1r + f[10] * x2rr;

        float s01 = f[1] * xj0 + f[6] * x1r;
#pragma unroll
        for (int a = 0; a < 3; a++)
            A1[a] += s01 * h[a] + f[3] * xv[a] + f[8] * x2r[a];

        float f2x = f[2] * xj0;
#pragma unroll
        for (int a = 0; a < 3; a++) {
#pragma unroll
            for (int b = 0; b < 3; b++) {
                A2[a * 3 + b] += f2x * h[a] * h[b] + f[4] * xv[a] * h[b]
                               + f[7] * T[a * 3 + b] + f[9] * x2r[a] * h[b];
            }
        }
    }

    // ---- self-interaction + gates + residual (per node, cross-channel via LDS) ----
    sa0[ln][c] = A0;
#pragma unroll
    for (int a = 0; a < 3; a++) sa1[ln][c][a] = A1[a];
#pragma unroll
    for (int q = 0; q < 9; q++) sa2[ln][c][q] = A2[q];
    __syncthreads();

    int d = c;  // this thread produces output channel d of node n

    float y0 = 0.0f;
#pragma unroll 8
    for (int cc = 0; cc < CH; cc++) y0 = fmaf(sa0[ln][cc], Wmix0[cc * CH + d], y0);
    float cp0 = coupling[0 * CH + d], cp1 = coupling[1 * CH + d], cp2 = coupling[2 * CH + d];
    float cp3 = coupling[3 * CH + d], cp4 = coupling[4 * CH + d], cp5 = coupling[5 * CH + d];
    float cp6 = coupling[6 * CH + d], cp7 = coupling[7 * CH + d];
    float n1 = A1[0] * A1[0] + A1[1] * A1[1] + A1[2] * A1[2];
    float n2 = 0.0f;
#pragma unroll
    for (int q = 0; q < 9; q++) n2 = fmaf(A2[q], A2[q], n2);
    y0 += cp0 * A0 * A0 + cp3 * n1 + cp6 * n2;
    sy0[ln][d] = y0;

    float y1[3] = {0, 0, 0};
#pragma unroll 4
    for (int cc = 0; cc < CH; cc++) {
        float w = Wmix1[cc * CH + d];
#pragma unroll
        for (int a = 0; a < 3; a++) y1[a] = fmaf(sa1[ln][cc][a], w, y1[a]);
    }
#pragma unroll
    for (int a = 0; a < 3; a++) {
        float a2a1 = A2[a * 3 + 0] * A1[0] + A2[a * 3 + 1] * A1[1] + A2[a * 3 + 2] * A1[2];
        y1[a] += cp1 * A0 * A1[a] + cp5 * a2a1;
    }

    float y2[9] = {0, 0, 0, 0, 0, 0, 0, 0, 0};
#pragma unroll 2
    for (int cc = 0; cc < CH; cc++) {
        float w = Wmix2[cc * CH + d];
#pragma unroll
        for (int q = 0; q < 9; q++) y2[q] = fmaf(sa2[ln][cc][q], w, y2[q]);
    }
#pragma unroll
    for (int a = 0; a < 3; a++) {
#pragma unroll
        for (int b = 0; b < 3; b++) {
            float a2a2 = A2[a * 3 + 0] * A2[0 * 3 + b] + A2[a * 3 + 1] * A2[1 * 3 + b]
                       + A2[a * 3 + 2] * A2[2 * 3 + b];
            y2[a * 3 + b] += cp2 * A0 * A2[a * 3 + b] + cp4 * A1[a] * A1[b] + cp7 * a2a2;
        }
    }

    __syncthreads();  // sy0 complete

    float g0 = bg0[d], g1 = bg1[d], g2 = bg2[d];
#pragma unroll 8
    for (int cc = 0; cc < CH; cc++) {
        float yv = sy0[ln][cc];
        g0 = fmaf(yv, Wg0[cc * CH + d], g0);
        g1 = fmaf(yv, Wg1[cc * CH + d], g1);
        g2 = fmaf(yv, Wg2[cc * CH + d], g2);
    }
    g0 = silu_f(g0);
    g1 = silu_f(g1);
    g2 = silu_f(g2);

    if (valid) {
        float* o = &out[(size_t)(n * CH + d) * 13];
        o[0] = x0[n * CH + d] + g0;
#pragma unroll
        for (int a = 0; a < 3; a++) o[1 + a] = x1[(n * CH + d) * 3 + a] + y1[a] * g1;
#pragma unroll
        for (int q = 0; q < 9; q++) o[4 + q] = x2[(n * CH + d) * 9 + q] + y2[q] * g2;
    }
}

extern "C" void kernel_launch(void* const* d_in, const int* in_sizes, int n_in,
                              void* d_out, int out_size, void* d_ws, size_t ws_size,
                              hipStream_t stream) {
    const float* rij      = (const float*)d_in[0];
    const float* x0       = (const float*)d_in[1];
    const float* x1       = (const float*)d_in[2];
    const float* x2       = (const float*)d_in[3];
    const int*   idx_i    = (const int*)d_in[4];
    const int*   idx_j    = (const int*)d_in[5];
    const float* W_rbf    = (const float*)d_in[6];
    const float* b_rbf    = (const float*)d_in[7];
    const float* Wmix0    = (const float*)d_in[8];
    const float* Wmix1    = (const float*)d_in[9];
    const float* Wmix2    = (const float*)d_in[10];
    const float* coupling = (const float*)d_in[11];
    const float* Wg0      = (const float*)d_in[12];
    const float* Wg1      = (const float*)d_in[13];
    const float* Wg2      = (const float*)d_in[14];
    const float* bg0      = (const float*)d_in[15];
    const float* bg1      = (const float*)d_in[16];
    const float* bg2      = (const float*)d_in[17];

    int E = in_sizes[4];
    int N = in_sizes[1] / CH;

    // workspace: counts[N] | offsets[N+1] | cursor[N] | perm[E]
    int* counts  = (int*)d_ws;
    int* offsets = counts + N;
    int* cursor  = offsets + (N + 1);
    int* perm    = cursor + N;

    hipMemsetAsync(counts, 0, (size_t)N * sizeof(int), stream);

    int eblocks = (E + 255) / 256;
    hist_kernel<<<eblocks, 256, 0, stream>>>(idx_i, counts, E);
    scan_kernel<<<1, 1024, 0, stream>>>(counts, offsets, cursor, N);
    fill_kernel<<<eblocks, 256, 0, stream>>>(idx_i, cursor, perm, E);

    int nblocks = (N + 7) / 8;
    fused_kernel<<<nblocks, 256, 0, stream>>>(rij, x0, x1, x2, idx_j, offsets, perm,
                                              W_rbf, b_rbf, Wmix0, Wmix1, Wmix2, coupling,
                                              Wg0, Wg1, Wg2, bg0, bg1, bg2,
                                              (float*)d_out, N);
}

// Round 3
// 331.765 us; speedup vs baseline: 6.5666x; 1.0186x over previous
//
#include <hip/hip_runtime.h>
#include <cmath>

#define CH 32
#define NBASIS 8
#define NPATH 11

__device__ __forceinline__ float silu_f(float x) {
    return x / (1.0f + __expf(-x));
}

// ---------- CSR build ----------
__global__ __launch_bounds__(256) void hist_kernel(const int* __restrict__ idx_i,
                                                   int* __restrict__ counts, int E) {
    int e = blockIdx.x * blockDim.x + threadIdx.x;
    if (e < E) atomicAdd(&counts[idx_i[e]], 1);
}

// Single-block exclusive scan over N counts -> offsets[N+1], cursor[N]
__global__ __launch_bounds__(1024) void scan_kernel(const int* __restrict__ counts,
                                                    int* __restrict__ offsets,
                                                    int* __restrict__ cursor, int N) {
    __shared__ int part[1024];
    int t = threadIdx.x;
    int per = (N + 1023) / 1024;
    int start = t * per;
    int local = 0;
    for (int k = 0; k < per; k++) {
        int idx = start + k;
        if (idx < N) local += counts[idx];
    }
    part[t] = local;
    __syncthreads();
    for (int off = 1; off < 1024; off <<= 1) {
        int v = (t >= off) ? part[t - off] : 0;
        __syncthreads();
        part[t] += v;
        __syncthreads();
    }
    int base = (t == 0) ? 0 : part[t - 1];
    for (int k = 0; k < per; k++) {
        int idx = start + k;
        if (idx < N) {
            offsets[idx] = base;
            cursor[idx]  = base;
            base += counts[idx];
        }
    }
    if (t == 0) offsets[N] = part[1023];
}

// Per-edge: compute geometry + scaled RBF once, scatter a 64 B record to CSR slot.
// record (4 x float4): {hx,hy,hz,scale} {rbfS0..3} {rbfS4..7} {j_bits, -, -, -}
__global__ __launch_bounds__(256) void fill_records(
    const float* __restrict__ rij,
    const int*   __restrict__ idx_i,
    const int*   __restrict__ idx_j,
    int*   __restrict__ cursor,
    float4* __restrict__ recs, int E)
{
    int e = blockIdx.x * blockDim.x + threadIdx.x;
    if (e >= E) return;

    float rx = rij[e * 3 + 0], ry = rij[e * 3 + 1], rz = rij[e * 3 + 2];
    float dn = sqrtf(rx * rx + ry * ry + rz * rz);
    float d = fmaxf(dn, 1e-6f);
    float inv = 1.0f / d;
    float hx = rx * inv, hy = ry * inv, hz = rz * inv;

    float rbf[NBASIS];
#pragma unroll
    for (int k = 0; k < NBASIS; k++) {
        float ck = 5.0f * (float)k / (float)(NBASIS - 1);
        float del = d - ck;
        rbf[k] = __expf(-4.0f * del * del);
    }
    float dc = fminf(d, 5.0f);
    float fc = 0.5f * (__cosf((float)M_PI * dc * 0.2f) + 1.0f);
    float scale = fc * 0.1f;   // cutoff * 1/NORM_FACTOR, folded into filters

    int pos = atomicAdd(&cursor[idx_i[e]], 1);
    float4* r = recs + 4 * (size_t)pos;
    r[0] = make_float4(hx, hy, hz, scale);
    r[1] = make_float4(rbf[0] * scale, rbf[1] * scale, rbf[2] * scale, rbf[3] * scale);
    r[2] = make_float4(rbf[4] * scale, rbf[5] * scale, rbf[6] * scale, rbf[7] * scale);
    r[3] = make_float4(__int_as_float(idx_j[e]), 0.0f, 0.0f, 0.0f);
}

// ---------- fused gather + self-interaction ----------
// One node per wave64: lanes 0-31 = channels (even edges), lanes 32-63 = channels (odd edges).
__global__ __launch_bounds__(256) void fused_kernel(
    const float4* __restrict__ recs,
    const float* __restrict__ x0,      // [N,C]
    const float* __restrict__ x1,      // [N,C,3]
    const float* __restrict__ x2,      // [N,C,9]
    const int*   __restrict__ offsets, // [N+1]
    const float* __restrict__ W_rbf,   // [NBASIS, NPATH*C]
    const float* __restrict__ b_rbf,   // [NPATH*C]
    const float* __restrict__ Wmix0, const float* __restrict__ Wmix1, const float* __restrict__ Wmix2,
    const float* __restrict__ coupling,
    const float* __restrict__ Wg0, const float* __restrict__ Wg1, const float* __restrict__ Wg2,
    const float* __restrict__ bg0, const float* __restrict__ bg1, const float* __restrict__ bg2,
    float* __restrict__ out, int N)
{
    const int NW = 4;  // waves (=nodes) per 256-thread block
    __shared__ float sa0[NW][CH];
    __shared__ float sa1[NW][CH][3];
    __shared__ float sa2[NW][CH][9];
    __shared__ float sy0[NW][CH];

    int wid  = threadIdx.x >> 6;
    int lane = threadIdx.x & 63;
    int half = lane >> 5;
    int c    = lane & 31;
    int n    = blockIdx.x * NW + wid;
    bool valid = (n < N);

    float A0 = 0.0f, A1[3] = {0, 0, 0}, A2[9] = {0, 0, 0, 0, 0, 0, 0, 0, 0};

    int kbeg = 0, kend = 0;
    if (valid) { kbeg = offsets[n]; kend = offsets[n + 1]; }

    int k = kbeg + half;
    float4 c0, c1, c2, c3;
    bool have = (k < kend);
    if (have) {
        const float4* r = recs + 4 * (size_t)k;
        c0 = r[0]; c1 = r[1]; c2 = r[2]; c3 = r[3];
    }

    while (have) {
        int j = __float_as_int(c3.x);

        // issue all gathers for this edge up front (j known from previous iter's load)
        float xj0 = x0[j * CH + c];
        float xv[3];
#pragma unroll
        for (int a = 0; a < 3; a++) xv[a] = x1[(j * CH + c) * 3 + a];
        float T[9];
#pragma unroll
        for (int q = 0; q < 9; q++) T[q] = x2[(j * CH + c) * 9 + q];

        // prefetch next record (2 ahead in CSR order = next for this half)
        int k2 = k + 2;
        bool have2 = (k2 < kend);
        float4 n0, n1, n2, n3;
        if (have2) {
            const float4* r2 = recs + 4 * (size_t)k2;
            n0 = r2[0]; n1 = r2[1]; n2 = r2[2]; n3 = r2[3];
        }

        // filters: f[p] = scale*b + sum_k rbfS[k]*W[k][p*CH+c]
        float f[NPATH];
#pragma unroll
        for (int p = 0; p < NPATH; p++) {
            int col = p * CH + c;
            float acc = c0.w * b_rbf[col];
            acc = fmaf(c1.x, W_rbf[0 * (NPATH * CH) + col], acc);
            acc = fmaf(c1.y, W_rbf[1 * (NPATH * CH) + col], acc);
            acc = fmaf(c1.z, W_rbf[2 * (NPATH * CH) + col], acc);
            acc = fmaf(c1.w, W_rbf[3 * (NPATH * CH) + col], acc);
            acc = fmaf(c2.x, W_rbf[4 * (NPATH * CH) + col], acc);
            acc = fmaf(c2.y, W_rbf[5 * (NPATH * CH) + col], acc);
            acc = fmaf(c2.z, W_rbf[6 * (NPATH * CH) + col], acc);
            acc = fmaf(c2.w, W_rbf[7 * (NPATH * CH) + col], acc);
            f[p] = acc;
        }

        float h[3] = {c0.x, c0.y, c0.z};
        float x1r = xv[0] * h[0] + xv[1] * h[1] + xv[2] * h[2];
        float x2r[3];
#pragma unroll
        for (int a = 0; a < 3; a++)
            x2r[a] = T[a * 3 + 0] * h[0] + T[a * 3 + 1] * h[1] + T[a * 3 + 2] * h[2];
        float x2rr = x2r[0] * h[0] + x2r[1] * h[1] + x2r[2] * h[2];

        A0 += f[0] * xj0 + f[5] * x1r + f[10] * x2rr;

        float s01 = f[1] * xj0 + f[6] * x1r;
#pragma unroll
        for (int a = 0; a < 3; a++)
            A1[a] += s01 * h[a] + f[3] * xv[a] + f[8] * x2r[a];

        float f2x = f[2] * xj0;
#pragma unroll
        for (int a = 0; a < 3; a++) {
            float w = f2x * h[a] + f[4] * xv[a] + f[9] * x2r[a];
#pragma unroll
            for (int b = 0; b < 3; b++)
                A2[a * 3 + b] += w * h[b] + f[7] * T[a * 3 + b];
        }

        k = k2; c0 = n0; c1 = n1; c2 = n2; c3 = n3; have = have2;
    }

    // combine even/odd halves
    A0 += __shfl_xor(A0, 32);
#pragma unroll
    for (int a = 0; a < 3; a++) A1[a] += __shfl_xor(A1[a], 32);
#pragma unroll
    for (int q = 0; q < 9; q++) A2[q] += __shfl_xor(A2[q], 32);

    bool epi = (half == 0) && valid;
    if (epi) {
        sa0[wid][c] = A0;
#pragma unroll
        for (int a = 0; a < 3; a++) sa1[wid][c][a] = A1[a];
#pragma unroll
        for (int q = 0; q < 9; q++) sa2[wid][c][q] = A2[q];
    }
    __syncthreads();

    int d = c;
    float y0 = 0.0f;
    float y1[3] = {0, 0, 0};
    float y2[9] = {0, 0, 0, 0, 0, 0, 0, 0, 0};

    if (epi) {
#pragma unroll 8
        for (int cc = 0; cc < CH; cc++) y0 = fmaf(sa0[wid][cc], Wmix0[cc * CH + d], y0);
        float cp0 = coupling[0 * CH + d], cp3 = coupling[3 * CH + d], cp6 = coupling[6 * CH + d];
        float n1v = A1[0] * A1[0] + A1[1] * A1[1] + A1[2] * A1[2];
        float n2v = 0.0f;
#pragma unroll
        for (int q = 0; q < 9; q++) n2v = fmaf(A2[q], A2[q], n2v);
        y0 += cp0 * A0 * A0 + cp3 * n1v + cp6 * n2v;
        sy0[wid][d] = y0;

#pragma unroll 4
        for (int cc = 0; cc < CH; cc++) {
            float w = Wmix1[cc * CH + d];
#pragma unroll
            for (int a = 0; a < 3; a++) y1[a] = fmaf(sa1[wid][cc][a], w, y1[a]);
        }
        float cp1 = coupling[1 * CH + d], cp5 = coupling[5 * CH + d];
#pragma unroll
        for (int a = 0; a < 3; a++) {
            float a2a1 = A2[a * 3 + 0] * A1[0] + A2[a * 3 + 1] * A1[1] + A2[a * 3 + 2] * A1[2];
            y1[a] += cp1 * A0 * A1[a] + cp5 * a2a1;
        }

#pragma unroll 2
        for (int cc = 0; cc < CH; cc++) {
            float w = Wmix2[cc * CH + d];
#pragma unroll
            for (int q = 0; q < 9; q++) y2[q] = fmaf(sa2[wid][cc][q], w, y2[q]);
        }
        float cp2 = coupling[2 * CH + d], cp4 = coupling[4 * CH + d], cp7 = coupling[7 * CH + d];
#pragma unroll
        for (int a = 0; a < 3; a++) {
#pragma unroll
            for (int b = 0; b < 3; b++) {
                float a2a2 = A2[a * 3 + 0] * A2[0 * 3 + b] + A2[a * 3 + 1] * A2[1 * 3 + b]
                           + A2[a * 3 + 2] * A2[2 * 3 + b];
                y2[a * 3 + b] += cp2 * A0 * A2[a * 3 + b] + cp4 * A1[a] * A1[b] + cp7 * a2a2;
            }
        }
    }
    __syncthreads();  // sy0 complete

    if (epi) {
        float g0 = bg0[d], g1 = bg1[d], g2 = bg2[d];
#pragma unroll 8
        for (int cc = 0; cc < CH; cc++) {
            float yv = sy0[wid][cc];
            g0 = fmaf(yv, Wg0[cc * CH + d], g0);
            g1 = fmaf(yv, Wg1[cc * CH + d], g1);
            g2 = fmaf(yv, Wg2[cc * CH + d], g2);
        }
        g0 = silu_f(g0);
        g1 = silu_f(g1);
        g2 = silu_f(g2);

        float* o = &out[(size_t)(n * CH + d) * 13];
        o[0] = x0[n * CH + d] + g0;
#pragma unroll
        for (int a = 0; a < 3; a++) o[1 + a] = x1[(n * CH + d) * 3 + a] + y1[a] * g1;
#pragma unroll
        for (int q = 0; q < 9; q++) o[4 + q] = x2[(n * CH + d) * 9 + q] + y2[q] * g2;
    }
}

extern "C" void kernel_launch(void* const* d_in, const int* in_sizes, int n_in,
                              void* d_out, int out_size, void* d_ws, size_t ws_size,
                              hipStream_t stream) {
    const float* rij      = (const float*)d_in[0];
    const float* x0       = (const float*)d_in[1];
    const float* x1       = (const float*)d_in[2];
    const float* x2       = (const float*)d_in[3];
    const int*   idx_i    = (const int*)d_in[4];
    const int*   idx_j    = (const int*)d_in[5];
    const float* W_rbf    = (const float*)d_in[6];
    const float* b_rbf    = (const float*)d_in[7];
    const float* Wmix0    = (const float*)d_in[8];
    const float* Wmix1    = (const float*)d_in[9];
    const float* Wmix2    = (const float*)d_in[10];
    const float* coupling = (const float*)d_in[11];
    const float* Wg0      = (const float*)d_in[12];
    const float* Wg1      = (const float*)d_in[13];
    const float* Wg2      = (const float*)d_in[14];
    const float* bg0      = (const float*)d_in[15];
    const float* bg1      = (const float*)d_in[16];
    const float* bg2      = (const float*)d_in[17];

    int E = in_sizes[4];
    int N = in_sizes[1] / CH;

    // ws layout: recs[E*4 float4] (16B aligned at base) | counts[N] | offsets[N+1] | cursor[N]
    float4* recs   = (float4*)d_ws;
    int* counts    = (int*)(recs + (size_t)E * 4);
    int* offsets   = counts + N;
    int* cursor    = offsets + (N + 1);

    hipMemsetAsync(counts, 0, (size_t)N * sizeof(int), stream);

    int eblocks = (E + 255) / 256;
    hist_kernel<<<eblocks, 256, 0, stream>>>(idx_i, counts, E);
    scan_kernel<<<1, 1024, 0, stream>>>(counts, offsets, cursor, N);
    fill_records<<<eblocks, 256, 0, stream>>>(rij, idx_i, idx_j, cursor, recs, E);

    int nblocks = (N + 3) / 4;
    fused_kernel<<<nblocks, 256, 0, stream>>>(recs, x0, x1, x2, offsets,
                                              W_rbf, b_rbf, Wmix0, Wmix1, Wmix2, coupling,
                                              Wg0, Wg1, Wg2, bg0, bg1, bg2,
                                              (float*)d_out, N);
}